// Round 1
// 823.103 us; speedup vs baseline: 1.0739x; 1.0739x over previous
//
#include <hip/hip_runtime.h>
#include <stdint.h>
#include <stddef.h>

// ---------- types ----------
typedef __attribute__((ext_vector_type(8))) short bf16x8;  // 8 bf16 (4 VGPRs)
typedef __attribute__((ext_vector_type(4))) short bf16x4;
typedef __attribute__((ext_vector_type(4))) float f32x4;

typedef const __attribute__((address_space(1))) uint32_t gas_u32;
typedef __attribute__((address_space(3))) uint32_t las_u32;

__device__ __forceinline__ short f2bf(float f) {
  union { float f; uint32_t u; } c; c.f = f;
  uint32_t u = c.u;
  u += 0x7fffu + ((u >> 16) & 1u);   // RNE
  return (short)(u >> 16);
}

// ---------- fp32 -> bf16 convert ----------
__global__ void k_cvt(const float* __restrict__ src, short* __restrict__ dst, int n) {
  int i = (blockIdx.x * 256 + threadIdx.x) * 4;
  if (i + 4 <= n) {
    float4 v = *(const float4*)(src + i);
    bf16x4 o = { f2bf(v.x), f2bf(v.y), f2bf(v.z), f2bf(v.w) };
    *(bf16x4*)(dst + i) = o;
  } else {
    for (; i < n; ++i) dst[i] = f2bf(src[i]);
  }
}

// gather rows [row0, row0+rpb) of each batch's (93,2048) context into packed (8*rpb,2048) bf16
__global__ void k_cvt_ctx(const float* __restrict__ ctx, short* __restrict__ dst,
                          int rpb, int row0) {
  long total = 8L * rpb * 2048;
  long i = ((long)blockIdx.x * 256 + threadIdx.x) * 4;
  if (i >= total) return;
  int c = (int)(i & 2047);
  long rs = i >> 11;
  int b = (int)(rs / rpb);
  int s = (int)(rs - (long)b * rpb);
  const float* sp = ctx + ((long)(b * 93 + row0 + s) * 2048 + c);
  float4 v = *(const float4*)sp;
  bf16x4 o = { f2bf(v.x), f2bf(v.y), f2bf(v.z), f2bf(v.w) };
  *(bf16x4*)(dst + i) = o;
}

// ---------- GEMM helpers ----------
// fragment loads (ds_read_b128, XOR-swizzled layout) kept separate from the MFMA
// block so the next tile's global_load_lds can be issued between them: source
// order = ds_read(cur) -> stage(next) -> mfma(cur) -> one __syncthreads per K-step.
struct GFrag { bf16x8 a[4]; bf16x8 b[4]; };

__device__ __forceinline__ void g_ld(GFrag& f, const short* as, const short* bs,
                                     int wm, int wn, int r16, int swz) {
#pragma unroll
  for (int i = 0; i < 4; ++i)
    f.a[i] = *(const bf16x8*)(as + (wm + i * 16 + r16) * 32 + swz);
#pragma unroll
  for (int j = 0; j < 4; ++j)
    f.b[j] = *(const bf16x8*)(bs + (wn + j * 16 + r16) * 32 + swz);
}

__device__ __forceinline__ void g_mm(const GFrag& f, f32x4 acc[4][4]) {
#pragma unroll
  for (int i = 0; i < 4; ++i)
#pragma unroll
    for (int j = 0; j < 4; ++j)
      acc[i][j] = __builtin_amdgcn_mfma_f32_16x16x32_bf16(f.a[i], f.b[j], acc[i][j], 0, 0, 0);
}

__device__ __forceinline__ void g_stage(short* asd, short* bsd,
                                        const short* ga0, const short* ga1,
                                        const short* gb0, const short* gb1,
                                        int k0, int p0, int p1) {
  __builtin_amdgcn_global_load_lds((gas_u32*)(ga0 + k0), (las_u32*)(asd + p0 * 8), 16, 0, 0);
  __builtin_amdgcn_global_load_lds((gas_u32*)(ga1 + k0), (las_u32*)(asd + p1 * 8), 16, 0, 0);
  __builtin_amdgcn_global_load_lds((gas_u32*)(gb0 + k0), (las_u32*)(bsd + p0 * 8), 16, 0, 0);
  __builtin_amdgcn_global_load_lds((gas_u32*)(gb1 + k0), (las_u32*)(bsd + p1 * 8), 16, 0, 0);
}

// ---------- GEMM: C[M,N] = A[M,K] * B[N,K]^T  (both row-major, bf16, fp32 acc) ----------
// LDS layout is XOR-swizzled: within each 64B row (4x 16B chunks), global chunk c
// of row r is stored at slot c ^ ((r>>1)&3)  (max 2-way bank alias = free, m136).
// Double-buffered (2-phase T3-minimum): stage tile t+1 while computing tile t;
// single __syncthreads per K-step drains vmcnt(0) AFTER the MFMAs, so the
// global_load_lds latency hides under compute. Requires K % 64 == 0.
// MODE 0: store bf16 head-permuted: grp = h/20 selects K vs V half (grp always 0 for Q):
//         out[((grp*160 + b*20 + h%20)*SPB + s)*64 + d],  h=n>>6, d=n&63
// MODE 1: store fp32 row-major + bias[n]
template <int MODE>
__global__ __launch_bounds__(256)
void k_gemm(const short* __restrict__ A, const short* __restrict__ Bm,
            void* __restrict__ out, const float* __restrict__ bias,
            int Mreal, int N, int K, int SPB) {
  __shared__ __align__(16) short As[2][128 * 32];
  __shared__ __align__(16) short Bs[2][128 * 32];
  const int t = threadIdx.x;
  const int lane = t & 63, wave = t >> 6;
  const int wm = (wave >> 1) * 64, wn = (wave & 1) * 64;

  // XCD-aware bijective tile remap (m204): HW dispatch id lin -> XCD = lin&7;
  // give each XCD a CONTIGUOUS run of work ids so the gridDim.x N-tiles that
  // share one A-panel land on the same XCD's L2 (they are consecutive work ids,
  // x fastest). Handles nwg % 8 != 0 (KV GEMMs: nwg = 100, 20).
  const int nwg = gridDim.x * gridDim.y;
  const int lin = blockIdx.y * gridDim.x + blockIdx.x;
  const int qq = nwg >> 3, r8 = nwg & 7;
  const int xcd = lin & 7, idx = lin >> 3;
  const int wg = (xcd < r8 ? xcd * (qq + 1) : r8 * (qq + 1) + (xcd - r8) * qq) + idx;
  const int bx = wg % gridDim.x, by = wg / gridDim.x;
  const int m0 = by * 128, n0 = bx * 128;
  const int q4 = lane >> 4, r16 = lane & 15;

  f32x4 zero = {0.f, 0.f, 0.f, 0.f};
  f32x4 acc[4][4];
#pragma unroll
  for (int i = 0; i < 4; ++i)
#pragma unroll
    for (int j = 0; j < 4; ++j) acc[i][j] = zero;

  // staging: 512 16B chunks per tile over 256 threads (2 each). LDS dest is
  // lane-contiguous (global_load_lds constraint); global source chunk is
  // swizzle-permuted so readers see slot = c ^ ((r>>1)&3).
  const int p0 = t, p1 = t + 256;
  const int ar0 = p0 >> 2, ac0 = (((p0 & 3) ^ ((ar0 >> 1) & 3))) * 8;
  const int ar1 = p1 >> 2, ac1 = (((p1 & 3) ^ ((ar1 >> 1) & 3))) * 8;
  int gm0 = m0 + ar0; if (gm0 >= Mreal) gm0 = Mreal - 1;
  int gm1 = m0 + ar1; if (gm1 >= Mreal) gm1 = Mreal - 1;
  const short* ga0 = A + (size_t)gm0 * K + ac0;
  const short* ga1 = A + (size_t)gm1 * K + ac1;
  const short* gb0 = Bm + (size_t)(n0 + ar0) * K + ac0;
  const short* gb1 = Bm + (size_t)(n0 + ar1) * K + ac1;

  // reader swizzle: slot for chunk q4 of row (…+r16); wave-uniform per lane,
  // loop-invariant (row base is a multiple of 16, so (row>>1)&3 == (r16>>1)&3)
  const int swz = (q4 ^ ((r16 >> 1) & 3)) * 8;

  // prologue: fill buffer 0
  g_stage(&As[0][0], &Bs[0][0], ga0, ga1, gb0, gb1, 0, p0, p1);
  __syncthreads();

  GFrag f;
  // steady state, 2 K-steps per iteration (static buffer indices; K%64==0)
  for (int k0 = 32; k0 < K - 32; k0 += 64) {
    g_ld(f, &As[0][0], &Bs[0][0], wm, wn, r16, swz);
    g_stage(&As[1][0], &Bs[1][0], ga0, ga1, gb0, gb1, k0, p0, p1);
    g_mm(f, acc);
    __syncthreads();   // drains vmcnt(0): buffer 1 ready; buffer 0 free to overwrite

    g_ld(f, &As[1][0], &Bs[1][0], wm, wn, r16, swz);
    g_stage(&As[0][0], &Bs[0][0], ga0, ga1, gb0, gb1, k0 + 32, p0, p1);
    g_mm(f, acc);
    __syncthreads();
  }
  // tail: stage last tile while computing second-to-last
  g_ld(f, &As[0][0], &Bs[0][0], wm, wn, r16, swz);
  g_stage(&As[1][0], &Bs[1][0], ga0, ga1, gb0, gb1, K - 32, p0, p1);
  g_mm(f, acc);
  __syncthreads();
  g_ld(f, &As[1][0], &Bs[1][0], wm, wn, r16, swz);
  g_mm(f, acc);

  // D layout (verified): row = q4*4 + reg, col = r16 within each 16x16 tile
  if (MODE == 0) {
    short* O = (short*)out;
#pragma unroll
    for (int i = 0; i < 4; ++i) {
#pragma unroll
      for (int rr = 0; rr < 4; ++rr) {
        int m = m0 + wm + i * 16 + q4 * 4 + rr;
        if (m < Mreal) {
          int bb, ss;
          if (SPB == 4096) { bb = m >> 12; ss = m & 4095; }
          else             { bb = m / SPB; ss = m - bb * SPB; }
#pragma unroll
          for (int j = 0; j < 4; ++j) {
            int n = n0 + wn + j * 16 + r16;
            int h = n >> 6, d = n & 63;
            int grp = (h >= 20) ? 1 : 0;        // K vs V half when N==2560
            int hl = h - grp * 20;
            O[(((size_t)(grp * 160 + bb * 20 + hl)) * SPB + ss) * 64 + d] = f2bf(acc[i][j][rr]);
          }
        }
      }
    }
  } else {
    float* O = (float*)out;
#pragma unroll
    for (int i = 0; i < 4; ++i) {
#pragma unroll
      for (int rr = 0; rr < 4; ++rr) {
        int m = m0 + wm + i * 16 + q4 * 4 + rr;
        if (m < Mreal) {
#pragma unroll
          for (int j = 0; j < 4; ++j) {
            int n = n0 + wn + j * 16 + r16;
            O[(size_t)m * N + n] = acc[i][j][rr] + bias[n];
          }
        }
      }
    }
  }
}

// ---------- fused dual attention: out = softmax(QKt^T/8)Vt + scale*softmax(QKi^T/8)Vi ----------
// Q,K,V in (b,h,s,64) bf16. Keys padded: rows 0..76 txt, 77..79 zero (masked), 80..95 img.
__global__ __launch_bounds__(256)
void k_attn(const short* __restrict__ qb, const short* __restrict__ kb,
            const short* __restrict__ vb, const short* __restrict__ kib,
            const short* __restrict__ vib, const float* __restrict__ scale_p,
            short* __restrict__ out) {
  constexpr int KS = 72;    // Ks row stride (shorts): 144B -> 2-way bank alias (free)
  constexpr int PS = 104;   // Vt/P row stride: 208B -> 2-way alias (free), 16B aligned
  __shared__ __align__(16) short Ks[96 * KS];
  __shared__ __align__(16) short Vt[64 * PS];      // transposed: Vt[d][key]
  __shared__ __align__(16) short Pp[4][16 * PS];   // per-wave P (A-layout staging)
  const int t = threadIdx.x, lane = t & 63, wave = t >> 6;
  const int q4 = lane >> 4, r16 = lane & 15;
  const int b = blockIdx.z, h = blockIdx.y, qt = blockIdx.x;
  const int bh = b * 20 + h;
  const short* kt = kb + (size_t)bh * 77 * 64;
  const short* vt = vb + (size_t)bh * 77 * 64;
  const short* ki = kib + (size_t)bh * 16 * 64;
  const short* vi = vib + (size_t)bh * 16 * 64;

  // stage K rows (16B chunks)
  for (int c = t; c < 96 * 8; c += 256) {
    int row = c >> 3, o = (c & 7) * 8;
    uint4 val = {0u, 0u, 0u, 0u};
    if (row < 77)       val = *(const uint4*)(kt + row * 64 + o);
    else if (row >= 80) val = *(const uint4*)(ki + (row - 80) * 64 + o);
    *(uint4*)(Ks + row * KS + o) = val;
  }
  // stage V transposed
  for (int i = t; i < 96 * 64; i += 256) {
    int key = i >> 6, d = i & 63;
    short v = 0;
    if (key < 77)       v = vt[key * 64 + d];
    else if (key >= 80) v = vi[(key - 80) * 64 + d];
    Vt[d * PS + key] = v;
  }
  __syncthreads();

  // per-wave: 16 q rows
  const int s0 = qt * 64 + wave * 16;
  const short* qp = qb + ((size_t)bh * 4096 + s0) * 64;
  bf16x8 qf[2];
#pragma unroll
  for (int kc = 0; kc < 2; ++kc)
    qf[kc] = *(const bf16x8*)(qp + r16 * 64 + kc * 32 + q4 * 8);

  f32x4 zero = {0.f, 0.f, 0.f, 0.f};
  f32x4 lg[6];  // logits tiles: 0..4 txt(80 padded), 5 img(16)
#pragma unroll
  for (int nt = 0; nt < 6; ++nt) {
    lg[nt] = zero;
#pragma unroll
    for (int kc = 0; kc < 2; ++kc) {
      bf16x8 kf = *(const bf16x8*)(Ks + (nt * 16 + r16) * KS + kc * 32 + q4 * 8);
      lg[nt] = __builtin_amdgcn_mfma_f32_16x16x32_bf16(qf[kc], kf, lg[nt], 0, 0, 0);
    }
  }

  const float sm = 0.125f;  // 1/sqrt(64)
  const float scl = scale_p[0];
#pragma unroll
  for (int nt = 0; nt < 6; ++nt)
#pragma unroll
    for (int rr = 0; rr < 4; ++rr) lg[nt][rr] *= sm;
  if (r16 >= 13) {  // txt tile 4: keys 64+r16 >= 77 are padding
#pragma unroll
    for (int rr = 0; rr < 4; ++rr) lg[4][rr] = -1e30f;
  }

  // two independent softmaxes; row rr lives in the 16 lanes of this quad at reg rr
#pragma unroll
  for (int rr = 0; rr < 4; ++rr) {
    float mx = -1e30f;
#pragma unroll
    for (int nt = 0; nt < 5; ++nt) mx = fmaxf(mx, lg[nt][rr]);
#pragma unroll
    for (int o = 1; o < 16; o <<= 1) mx = fmaxf(mx, __shfl_xor(mx, o, 64));
    float s = 0.f;
#pragma unroll
    for (int nt = 0; nt < 5; ++nt) {
      float p = __expf(lg[nt][rr] - mx);
      lg[nt][rr] = p; s += p;
    }
#pragma unroll
    for (int o = 1; o < 16; o <<= 1) s += __shfl_xor(s, o, 64);
    float inv = 1.f / s;
#pragma unroll
    for (int nt = 0; nt < 5; ++nt) lg[nt][rr] *= inv;

    float mi = lg[5][rr];
#pragma unroll
    for (int o = 1; o < 16; o <<= 1) mi = fmaxf(mi, __shfl_xor(mi, o, 64));
    float pi = __expf(lg[5][rr] - mi);
    float si = pi;
#pragma unroll
    for (int o = 1; o < 16; o <<= 1) si += __shfl_xor(si, o, 64);
    lg[5][rr] = pi * (scl / si);   // fold 'scale' into img probs
  }

  // C-layout -> A-layout via LDS round trip (wave-private, no barrier needed)
  short* pw = &Pp[wave][0];
#pragma unroll
  for (int nt = 0; nt < 6; ++nt)
#pragma unroll
    for (int rr = 0; rr < 4; ++rr)
      pw[(q4 * 4 + rr) * PS + nt * 16 + r16] = f2bf(lg[nt][rr]);

  // O = P(16x96) @ Vcat(96x64), img part pre-scaled
  f32x4 oc[4];
#pragma unroll
  for (int dt = 0; dt < 4; ++dt) {
    oc[dt] = zero;
#pragma unroll
    for (int kc = 0; kc < 3; ++kc) {
      bf16x8 pf = *(const bf16x8*)(pw + r16 * PS + kc * 32 + q4 * 8);
      bf16x8 vf = *(const bf16x8*)(Vt + (dt * 16 + r16) * PS + kc * 32 + q4 * 8);
      oc[dt] = __builtin_amdgcn_mfma_f32_16x16x32_bf16(pf, vf, oc[dt], 0, 0, 0);
    }
  }

  // store (b, s, h*64+d) bf16 for the output projection GEMM
#pragma unroll
  for (int dt = 0; dt < 4; ++dt)
#pragma unroll
    for (int rr = 0; rr < 4; ++rr) {
      int m = s0 + q4 * 4 + rr;
      int d = dt * 16 + r16;
      out[((size_t)b * 4096 + m) * 1280 + h * 64 + d] = f2bf(oc[dt][rr]);
    }
}

// ---------- launch ----------
extern "C" void kernel_launch(void* const* d_in, const int* in_sizes, int n_in,
                              void* d_out, int out_size, void* d_ws, size_t ws_size,
                              hipStream_t stream) {
  const float* x    = (const float*)d_in[0];
  const float* ctx  = (const float*)d_in[1];
  const float* scal = (const float*)d_in[2];
  // d_in[3] = num_img_token (fixed 16; eos = 77)
  const float* Wq   = (const float*)d_in[4];
  const float* Wk   = (const float*)d_in[5];
  const float* Wv   = (const float*)d_in[6];
  const float* Wkip = (const float*)d_in[7];
  const float* Wvip = (const float*)d_in[8];
  const float* Wout = (const float*)d_in[9];
  const float* bout = (const float*)d_in[10];
  float* out = (float*)d_out;

  char* ws = (char*)d_ws;
  size_t off = 0;
  auto alloc = [&](size_t elems) -> short* {
    short* p = (short*)(ws + off);
    off += (elems * 2 + 255) & ~(size_t)255;
    return p;
  };
  short* xb    = alloc(32768UL * 1280);   // also reused as attn output (x dead after Q proj)
  short* txtb  = alloc(616UL * 2048);
  short* imgb  = alloc(128UL * 2048);
  short* Wqb   = alloc(1280UL * 1280);
  // Wk|Wv contiguous (N=2560 merged KV projection); likewise Wkip|Wvip.
  // Each is 1280*2048*2 bytes = multiple of 256, so alloc() keeps them adjacent.
  short* Wkvb  = alloc(2UL * 1280 * 2048);
  short* Wkvip = alloc(2UL * 1280 * 2048);
  short* Woutb = alloc(1280UL * 1280);
  short* qb    = alloc(32768UL * 1280);   // (b,h,4096,64)
  short* kb    = alloc(2UL * 160 * 77 * 64);   // kb | vb adjacent (grp*160 indexing)
  short* kib   = alloc(2UL * 160 * 16 * 64);   // kib | vib adjacent
  short* vb    = kb  + 160UL * 77 * 64;
  short* vib   = kib + 160UL * 16 * 64;
  short* attnb = xb;

  auto cvt = [&](const float* s, short* d, long n) {
    int blocks = (int)((n / 4 + 255) / 256);
    k_cvt<<<blocks, 256, 0, stream>>>(s, d, (int)n);
  };
  cvt(x, xb, 32768L * 1280);
  cvt(Wq, Wqb, 1280L * 1280);
  cvt(Wk,   Wkvb,                 1280L * 2048);
  cvt(Wv,   Wkvb + 1280L * 2048,  1280L * 2048);
  cvt(Wkip, Wkvip,                1280L * 2048);
  cvt(Wvip, Wkvip + 1280L * 2048, 1280L * 2048);
  cvt(Wout, Woutb, 1280L * 1280);
  {
    long n1 = 8L * 77 * 2048;
    k_cvt_ctx<<<(int)((n1 / 4 + 255) / 256), 256, 0, stream>>>(ctx, txtb, 77, 0);
    long n2 = 8L * 16 * 2048;
    k_cvt_ctx<<<(int)((n2 / 4 + 255) / 256), 256, 0, stream>>>(ctx, imgb, 16, 77);
  }

  { dim3 g(10, 256); k_gemm<0><<<g, 256, 0, stream>>>(xb, Wqb, qb, nullptr, 32768, 1280, 1280, 4096); }
  { dim3 g(20, 5);
    k_gemm<0><<<g, 256, 0, stream>>>(txtb, Wkvb, kb, nullptr, 616, 2560, 2048, 77); }
  { dim3 g(20, 1);
    k_gemm<0><<<g, 256, 0, stream>>>(imgb, Wkvip, kib, nullptr, 128, 2560, 2048, 16); }
  { dim3 g(64, 20, 8);
    k_attn<<<g, 256, 0, stream>>>(qb, kb, vb, kib, vib, scal, attnb); }
  { dim3 g(10, 256);
    k_gemm<1><<<g, 256, 0, stream>>>(attnb, Woutb, out, bout, 32768, 1280, 1280, 1); }
}

// Round 2
// 784.147 us; speedup vs baseline: 1.1273x; 1.0497x over previous
//
#include <hip/hip_runtime.h>
#include <stdint.h>
#include <stddef.h>

// ---------- types ----------
typedef __attribute__((ext_vector_type(8))) short bf16x8;  // 8 bf16 (4 VGPRs)
typedef __attribute__((ext_vector_type(4))) short bf16x4;
typedef __attribute__((ext_vector_type(4))) float f32x4;

typedef const __attribute__((address_space(1))) uint32_t gas_u32;
typedef __attribute__((address_space(3))) uint32_t las_u32;

__device__ __forceinline__ short f2bf(float f) {
  union { float f; uint32_t u; } c; c.f = f;
  uint32_t u = c.u;
  u += 0x7fffu + ((u >> 16) & 1u);   // RNE
  return (short)(u >> 16);
}

// ---------- fp32 -> bf16 convert ----------
__global__ void k_cvt(const float* __restrict__ src, short* __restrict__ dst, int n) {
  int i = (blockIdx.x * 256 + threadIdx.x) * 4;
  if (i + 4 <= n) {
    float4 v = *(const float4*)(src + i);
    bf16x4 o = { f2bf(v.x), f2bf(v.y), f2bf(v.z), f2bf(v.w) };
    *(bf16x4*)(dst + i) = o;
  } else {
    for (; i < n; ++i) dst[i] = f2bf(src[i]);
  }
}

// gather rows [row0, row0+rpb) of each batch's (93,2048) context into packed (8*rpb,2048) bf16
__global__ void k_cvt_ctx(const float* __restrict__ ctx, short* __restrict__ dst,
                          int rpb, int row0) {
  long total = 8L * rpb * 2048;
  long i = ((long)blockIdx.x * 256 + threadIdx.x) * 4;
  if (i >= total) return;
  int c = (int)(i & 2047);
  long rs = i >> 11;
  int b = (int)(rs / rpb);
  int s = (int)(rs - (long)b * rpb);
  const float* sp = ctx + ((long)(b * 93 + row0 + s) * 2048 + c);
  float4 v = *(const float4*)sp;
  bf16x4 o = { f2bf(v.x), f2bf(v.y), f2bf(v.z), f2bf(v.w) };
  *(bf16x4*)(dst + i) = o;
}

// ---------- 128x128 GEMM helpers (kept for the small KV projections) ----------
struct GFrag { bf16x8 a[4]; bf16x8 b[4]; };

__device__ __forceinline__ void g_ld(GFrag& f, const short* as, const short* bs,
                                     int wm, int wn, int r16, int swz) {
#pragma unroll
  for (int i = 0; i < 4; ++i)
    f.a[i] = *(const bf16x8*)(as + (wm + i * 16 + r16) * 32 + swz);
#pragma unroll
  for (int j = 0; j < 4; ++j)
    f.b[j] = *(const bf16x8*)(bs + (wn + j * 16 + r16) * 32 + swz);
}

__device__ __forceinline__ void g_mm(const GFrag& f, f32x4 acc[4][4]) {
#pragma unroll
  for (int i = 0; i < 4; ++i)
#pragma unroll
    for (int j = 0; j < 4; ++j)
      acc[i][j] = __builtin_amdgcn_mfma_f32_16x16x32_bf16(f.a[i], f.b[j], acc[i][j], 0, 0, 0);
}

__device__ __forceinline__ void g_stage(short* asd, short* bsd,
                                        const short* ga0, const short* ga1,
                                        const short* gb0, const short* gb1,
                                        int k0, int p0, int p1) {
  __builtin_amdgcn_global_load_lds((gas_u32*)(ga0 + k0), (las_u32*)(asd + p0 * 8), 16, 0, 0);
  __builtin_amdgcn_global_load_lds((gas_u32*)(ga1 + k0), (las_u32*)(asd + p1 * 8), 16, 0, 0);
  __builtin_amdgcn_global_load_lds((gas_u32*)(gb0 + k0), (las_u32*)(bsd + p0 * 8), 16, 0, 0);
  __builtin_amdgcn_global_load_lds((gas_u32*)(gb1 + k0), (las_u32*)(bsd + p1 * 8), 16, 0, 0);
}

// ---------- GEMM 128x128 (2-phase dbuf): C[M,N] = A[M,K] * B[N,K]^T ----------
// Used only for the small KV projections (M=616/128). MODE 0 epilogue as before.
template <int MODE>
__global__ __launch_bounds__(256)
void k_gemm(const short* __restrict__ A, const short* __restrict__ Bm,
            void* __restrict__ out, const float* __restrict__ bias,
            int Mreal, int N, int K, int SPB) {
  __shared__ __align__(16) short As[2][128 * 32];
  __shared__ __align__(16) short Bs[2][128 * 32];
  const int t = threadIdx.x;
  const int lane = t & 63, wave = t >> 6;
  const int wm = (wave >> 1) * 64, wn = (wave & 1) * 64;

  const int nwg = gridDim.x * gridDim.y;
  const int lin = blockIdx.y * gridDim.x + blockIdx.x;
  const int qq = nwg >> 3, r8 = nwg & 7;
  const int xcd = lin & 7, idx = lin >> 3;
  const int wg = (xcd < r8 ? xcd * (qq + 1) : r8 * (qq + 1) + (xcd - r8) * qq) + idx;
  const int bx = wg % gridDim.x, by = wg / gridDim.x;
  const int m0 = by * 128, n0 = bx * 128;
  const int q4 = lane >> 4, r16 = lane & 15;

  f32x4 zero = {0.f, 0.f, 0.f, 0.f};
  f32x4 acc[4][4];
#pragma unroll
  for (int i = 0; i < 4; ++i)
#pragma unroll
    for (int j = 0; j < 4; ++j) acc[i][j] = zero;

  const int p0 = t, p1 = t + 256;
  const int ar0 = p0 >> 2, ac0 = (((p0 & 3) ^ ((ar0 >> 1) & 3))) * 8;
  const int ar1 = p1 >> 2, ac1 = (((p1 & 3) ^ ((ar1 >> 1) & 3))) * 8;
  int gm0 = m0 + ar0; if (gm0 >= Mreal) gm0 = Mreal - 1;
  int gm1 = m0 + ar1; if (gm1 >= Mreal) gm1 = Mreal - 1;
  const short* ga0 = A + (size_t)gm0 * K + ac0;
  const short* ga1 = A + (size_t)gm1 * K + ac1;
  const short* gb0 = Bm + (size_t)(n0 + ar0) * K + ac0;
  const short* gb1 = Bm + (size_t)(n0 + ar1) * K + ac1;

  const int swz = (q4 ^ ((r16 >> 1) & 3)) * 8;

  g_stage(&As[0][0], &Bs[0][0], ga0, ga1, gb0, gb1, 0, p0, p1);
  __syncthreads();

  GFrag f;
  for (int k0 = 32; k0 < K - 32; k0 += 64) {
    g_ld(f, &As[0][0], &Bs[0][0], wm, wn, r16, swz);
    g_stage(&As[1][0], &Bs[1][0], ga0, ga1, gb0, gb1, k0, p0, p1);
    g_mm(f, acc);
    __syncthreads();

    g_ld(f, &As[1][0], &Bs[1][0], wm, wn, r16, swz);
    g_stage(&As[0][0], &Bs[0][0], ga0, ga1, gb0, gb1, k0 + 32, p0, p1);
    g_mm(f, acc);
    __syncthreads();
  }
  g_ld(f, &As[0][0], &Bs[0][0], wm, wn, r16, swz);
  g_stage(&As[1][0], &Bs[1][0], ga0, ga1, gb0, gb1, K - 32, p0, p1);
  g_mm(f, acc);
  __syncthreads();
  g_ld(f, &As[1][0], &Bs[1][0], wm, wn, r16, swz);
  g_mm(f, acc);

  if (MODE == 0) {
    short* O = (short*)out;
#pragma unroll
    for (int i = 0; i < 4; ++i) {
#pragma unroll
      for (int rr = 0; rr < 4; ++rr) {
        int m = m0 + wm + i * 16 + q4 * 4 + rr;
        if (m < Mreal) {
          int bb, ss;
          if (SPB == 4096) { bb = m >> 12; ss = m & 4095; }
          else             { bb = m / SPB; ss = m - bb * SPB; }
#pragma unroll
          for (int j = 0; j < 4; ++j) {
            int n = n0 + wn + j * 16 + r16;
            int h = n >> 6, d = n & 63;
            int grp = (h >= 20) ? 1 : 0;
            int hl = h - grp * 20;
            O[(((size_t)(grp * 160 + bb * 20 + hl)) * SPB + ss) * 64 + d] = f2bf(acc[i][j][rr]);
          }
        }
      }
    }
  } else {
    float* O = (float*)out;
#pragma unroll
    for (int i = 0; i < 4; ++i) {
#pragma unroll
      for (int rr = 0; rr < 4; ++rr) {
        int m = m0 + wm + i * 16 + q4 * 4 + rr;
        if (m < Mreal) {
#pragma unroll
          for (int j = 0; j < 4; ++j) {
            int n = n0 + wn + j * 16 + r16;
            O[(size_t)m * N + n] = acc[i][j][rr] + bias[n];
          }
        }
      }
    }
  }
}

// ---------- GEMM 256x256, BK=64, 8 waves, 8-phase (T3+T4+T5): the big projections ----------
// Requires M%256==0, N%256==0, K%128==0.
// LDS: 2 dbuf x (A 256x64 + B 256x64) bf16 = 128 KiB -> 1 block/CU, 2 waves/SIMD.
// Chunk swizzle: row r's logical 16B chunk c lives at slot c ^ (r&7) within the
// 8-chunk (128B) row. Staging pre-permutes the GLOBAL source chunk so the
// lane-contiguous global_load_lds dest lands swizzled (both-sides rule, m104/m231).
// Read: within each 16-lane phase group, 8 slots x 2 rows = 2-way bank alias (free).
// Per K-tile: 4 phases x {4 ds_read A-frags, s_barrier, setprio(1), 16 MFMA,
// setprio(0), s_barrier}; B-frags (8 ds_read) hoisted to phase 0; next tile's
// 8 global_load_lds issued in phases 0-1 -> ~3 phases (~48 MFMA) of latency cover
// before the boundary __syncthreads drains vmcnt.
template <int MODE>
__global__ __launch_bounds__(512, 2)
void k_gemm256(const short* __restrict__ A, const short* __restrict__ Bm,
               void* __restrict__ out, const float* __restrict__ bias,
               int M, int N, int K, int SPB) {
  __shared__ __align__(16) short As[2][256 * 64];
  __shared__ __align__(16) short Bs[2][256 * 64];
  const int t = threadIdx.x;
  const int lane = t & 63;
  const int wave = t >> 6;
  const int q4 = lane >> 4, r16 = lane & 15;
  const int wm = (wave >> 2) * 128;   // 2 M-wave rows of 128
  const int wn = (wave & 3) * 64;     // 4 N-wave cols of 64

  // XCD-aware contiguous remap (nwg % 8 == 0 for both big GEMMs: 640 blocks)
  const int nwg = gridDim.x * gridDim.y;
  const int lin = blockIdx.y * gridDim.x + blockIdx.x;
  const int cpx = nwg >> 3;
  const int wg = (lin & 7) * cpx + (lin >> 3);
  const int bx = wg % gridDim.x, by = wg / gridDim.x;
  const int m0 = by * 256, n0 = bx * 256;

  // staging: thread t owns LDS chunks {t, t+512, t+1024, t+1536} of each of A,B.
  // LDS chunk p -> (row p>>3, slot p&7); source global chunk = (p&7) ^ (row&7).
  const int srow = t >> 3;
  const int csrc = (t & 7) ^ (srow & 7);
  const short* gA = A + (size_t)(m0 + srow) * K + csrc * 8;
  const short* gB = Bm + (size_t)(n0 + srow) * K + csrc * 8;
  const size_t rstep = (size_t)64 * K;

  // reader swizzle: logical chunk (kc*4 + q4) of row (... + r16) at slot ^ (r16&7)
  const int swz0 = ((q4) ^ (r16 & 7)) * 8;        // kc = 0
  const int swz1 = ((4 + q4) ^ (r16 & 7)) * 8;    // kc = 1

  f32x4 zero = {0.f, 0.f, 0.f, 0.f};
  f32x4 acc[8][4];
#pragma unroll
  for (int i = 0; i < 8; ++i)
#pragma unroll
    for (int j = 0; j < 4; ++j) acc[i][j] = zero;

  auto stageA = [&](short* buf, int k0) {
    __builtin_amdgcn_global_load_lds((gas_u32*)(gA + k0),             (las_u32*)(buf + (t          ) * 8), 16, 0, 0);
    __builtin_amdgcn_global_load_lds((gas_u32*)(gA + rstep + k0),     (las_u32*)(buf + (t +  512   ) * 8), 16, 0, 0);
    __builtin_amdgcn_global_load_lds((gas_u32*)(gA + 2 * rstep + k0), (las_u32*)(buf + (t + 1024   ) * 8), 16, 0, 0);
    __builtin_amdgcn_global_load_lds((gas_u32*)(gA + 3 * rstep + k0), (las_u32*)(buf + (t + 1536   ) * 8), 16, 0, 0);
  };
  auto stageB = [&](short* buf, int k0) {
    __builtin_amdgcn_global_load_lds((gas_u32*)(gB + k0),             (las_u32*)(buf + (t          ) * 8), 16, 0, 0);
    __builtin_amdgcn_global_load_lds((gas_u32*)(gB + rstep + k0),     (las_u32*)(buf + (t +  512   ) * 8), 16, 0, 0);
    __builtin_amdgcn_global_load_lds((gas_u32*)(gB + 2 * rstep + k0), (las_u32*)(buf + (t + 1024   ) * 8), 16, 0, 0);
    __builtin_amdgcn_global_load_lds((gas_u32*)(gB + 3 * rstep + k0), (las_u32*)(buf + (t + 1536   ) * 8), 16, 0, 0);
  };

  // one K-tile (BK=64), 4 phases; prefetch next tile's A in phase 0, B in phase 1
  auto tile = [&](const short* ca, const short* cb, bool pf, int k0n,
                  short* na, short* nb) {
    bf16x8 bfr[4][2];
#pragma unroll
    for (int q = 0; q < 4; ++q) {
      if (q == 0) {
#pragma unroll
        for (int j = 0; j < 4; ++j) {
          bfr[j][0] = *(const bf16x8*)(cb + (wn + j * 16 + r16) * 64 + swz0);
          bfr[j][1] = *(const bf16x8*)(cb + (wn + j * 16 + r16) * 64 + swz1);
        }
        if (pf) stageA(na, k0n);
      }
      if (q == 1 && pf) stageB(nb, k0n);
      bf16x8 a0k0 = *(const bf16x8*)(ca + (wm + (2 * q    ) * 16 + r16) * 64 + swz0);
      bf16x8 a0k1 = *(const bf16x8*)(ca + (wm + (2 * q    ) * 16 + r16) * 64 + swz1);
      bf16x8 a1k0 = *(const bf16x8*)(ca + (wm + (2 * q + 1) * 16 + r16) * 64 + swz0);
      bf16x8 a1k1 = *(const bf16x8*)(ca + (wm + (2 * q + 1) * 16 + r16) * 64 + swz1);
      __builtin_amdgcn_s_barrier();
      __builtin_amdgcn_s_setprio(1);
#pragma unroll
      for (int j = 0; j < 4; ++j) {
        acc[2 * q][j]     = __builtin_amdgcn_mfma_f32_16x16x32_bf16(a0k0, bfr[j][0], acc[2 * q][j], 0, 0, 0);
        acc[2 * q][j]     = __builtin_amdgcn_mfma_f32_16x16x32_bf16(a0k1, bfr[j][1], acc[2 * q][j], 0, 0, 0);
        acc[2 * q + 1][j] = __builtin_amdgcn_mfma_f32_16x16x32_bf16(a1k0, bfr[j][0], acc[2 * q + 1][j], 0, 0, 0);
        acc[2 * q + 1][j] = __builtin_amdgcn_mfma_f32_16x16x32_bf16(a1k1, bfr[j][1], acc[2 * q + 1][j], 0, 0, 0);
      }
      __builtin_amdgcn_s_setprio(0);
      if (q < 3) __builtin_amdgcn_s_barrier();
    }
  };

  // prologue: stage tile 0 into buf0
  stageA(&As[0][0], 0);
  stageB(&Bs[0][0], 0);
  __syncthreads();

  const int NT = K >> 6;   // K-tiles (even; K%128==0)
  for (int kt = 0; kt < NT; kt += 2) {
    const int k1 = (kt + 1) << 6;
    tile(&As[0][0], &Bs[0][0], k1 < K, k1, &As[1][0], &Bs[1][0]);
    __syncthreads();   // drains vmcnt(0): buf1 staged; buf0 free
    const int k2 = (kt + 2) << 6;
    tile(&As[1][0], &Bs[1][0], k2 < K, k2, &As[0][0], &Bs[0][0]);
    __syncthreads();
  }

  // epilogue. D layout: row = q4*4 + rr, col = r16 within each 16x16 tile.
  if (MODE == 0) {
    short* O = (short*)out;
#pragma unroll
    for (int i = 0; i < 8; ++i) {
#pragma unroll
      for (int rr = 0; rr < 4; ++rr) {
        int m = m0 + wm + i * 16 + q4 * 4 + rr;
        int bb, ss;
        if (SPB == 4096) { bb = m >> 12; ss = m & 4095; }
        else             { bb = m / SPB; ss = m - bb * SPB; }
#pragma unroll
        for (int j = 0; j < 4; ++j) {
          int n = n0 + wn + j * 16 + r16;
          int h = n >> 6, d = n & 63;
          int grp = (h >= 20) ? 1 : 0;
          int hl = h - grp * 20;
          O[(((size_t)(grp * 160 + bb * 20 + hl)) * SPB + ss) * 64 + d] = f2bf(acc[i][j][rr]);
        }
      }
    }
  } else {
    float* O = (float*)out;
#pragma unroll
    for (int i = 0; i < 8; ++i) {
#pragma unroll
      for (int rr = 0; rr < 4; ++rr) {
        int m = m0 + wm + i * 16 + q4 * 4 + rr;
#pragma unroll
        for (int j = 0; j < 4; ++j) {
          int n = n0 + wn + j * 16 + r16;
          O[(size_t)m * N + n] = acc[i][j][rr] + bias[n];
        }
      }
    }
  }
}

// ---------- fused dual attention: out = softmax(QKt^T/8)Vt + scale*softmax(QKi^T/8)Vi ----------
// Q,K,V in (b,h,s,64) bf16. Keys padded: rows 0..76 txt, 77..79 zero (masked), 80..95 img.
__global__ __launch_bounds__(256)
void k_attn(const short* __restrict__ qb, const short* __restrict__ kb,
            const short* __restrict__ vb, const short* __restrict__ kib,
            const short* __restrict__ vib, const float* __restrict__ scale_p,
            short* __restrict__ out) {
  constexpr int KS = 72;    // Ks row stride (shorts): 144B -> 2-way bank alias (free)
  constexpr int PS = 104;   // Vt/P row stride: 208B -> 2-way alias (free), 16B aligned
  __shared__ __align__(16) short Ks[96 * KS];
  __shared__ __align__(16) short Vt[64 * PS];      // transposed: Vt[d][key]
  __shared__ __align__(16) short Pp[4][16 * PS];   // per-wave P (A-layout staging)
  const int t = threadIdx.x, lane = t & 63, wave = t >> 6;
  const int q4 = lane >> 4, r16 = lane & 15;
  const int b = blockIdx.z, h = blockIdx.y, qt = blockIdx.x;
  const int bh = b * 20 + h;
  const short* kt = kb + (size_t)bh * 77 * 64;
  const short* vt = vb + (size_t)bh * 77 * 64;
  const short* ki = kib + (size_t)bh * 16 * 64;
  const short* vi = vib + (size_t)bh * 16 * 64;

  for (int c = t; c < 96 * 8; c += 256) {
    int row = c >> 3, o = (c & 7) * 8;
    uint4 val = {0u, 0u, 0u, 0u};
    if (row < 77)       val = *(const uint4*)(kt + row * 64 + o);
    else if (row >= 80) val = *(const uint4*)(ki + (row - 80) * 64 + o);
    *(uint4*)(Ks + row * KS + o) = val;
  }
  for (int i = t; i < 96 * 64; i += 256) {
    int key = i >> 6, d = i & 63;
    short v = 0;
    if (key < 77)       v = vt[key * 64 + d];
    else if (key >= 80) v = vi[(key - 80) * 64 + d];
    Vt[d * PS + key] = v;
  }
  __syncthreads();

  const int s0 = qt * 64 + wave * 16;
  const short* qp = qb + ((size_t)bh * 4096 + s0) * 64;
  bf16x8 qf[2];
#pragma unroll
  for (int kc = 0; kc < 2; ++kc)
    qf[kc] = *(const bf16x8*)(qp + r16 * 64 + kc * 32 + q4 * 8);

  f32x4 zero = {0.f, 0.f, 0.f, 0.f};
  f32x4 lg[6];
#pragma unroll
  for (int nt = 0; nt < 6; ++nt) {
    lg[nt] = zero;
#pragma unroll
    for (int kc = 0; kc < 2; ++kc) {
      bf16x8 kf = *(const bf16x8*)(Ks + (nt * 16 + r16) * KS + kc * 32 + q4 * 8);
      lg[nt] = __builtin_amdgcn_mfma_f32_16x16x32_bf16(qf[kc], kf, lg[nt], 0, 0, 0);
    }
  }

  const float sm = 0.125f;
  const float scl = scale_p[0];
#pragma unroll
  for (int nt = 0; nt < 6; ++nt)
#pragma unroll
    for (int rr = 0; rr < 4; ++rr) lg[nt][rr] *= sm;
  if (r16 >= 13) {
#pragma unroll
    for (int rr = 0; rr < 4; ++rr) lg[4][rr] = -1e30f;
  }

#pragma unroll
  for (int rr = 0; rr < 4; ++rr) {
    float mx = -1e30f;
#pragma unroll
    for (int nt = 0; nt < 5; ++nt) mx = fmaxf(mx, lg[nt][rr]);
#pragma unroll
    for (int o = 1; o < 16; o <<= 1) mx = fmaxf(mx, __shfl_xor(mx, o, 64));
    float s = 0.f;
#pragma unroll
    for (int nt = 0; nt < 5; ++nt) {
      float p = __expf(lg[nt][rr] - mx);
      lg[nt][rr] = p; s += p;
    }
#pragma unroll
    for (int o = 1; o < 16; o <<= 1) s += __shfl_xor(s, o, 64);
    float inv = 1.f / s;
#pragma unroll
    for (int nt = 0; nt < 5; ++nt) lg[nt][rr] *= inv;

    float mi = lg[5][rr];
#pragma unroll
    for (int o = 1; o < 16; o <<= 1) mi = fmaxf(mi, __shfl_xor(mi, o, 64));
    float pi = __expf(lg[5][rr] - mi);
    float si = pi;
#pragma unroll
    for (int o = 1; o < 16; o <<= 1) si += __shfl_xor(si, o, 64);
    lg[5][rr] = pi * (scl / si);
  }

  short* pw = &Pp[wave][0];
#pragma unroll
  for (int nt = 0; nt < 6; ++nt)
#pragma unroll
    for (int rr = 0; rr < 4; ++rr)
      pw[(q4 * 4 + rr) * PS + nt * 16 + r16] = f2bf(lg[nt][rr]);

  f32x4 oc[4];
#pragma unroll
  for (int dt = 0; dt < 4; ++dt) {
    oc[dt] = zero;
#pragma unroll
    for (int kc = 0; kc < 3; ++kc) {
      bf16x8 pf = *(const bf16x8*)(pw + r16 * PS + kc * 32 + q4 * 8);
      bf16x8 vf = *(const bf16x8*)(Vt + (dt * 16 + r16) * PS + kc * 32 + q4 * 8);
      oc[dt] = __builtin_amdgcn_mfma_f32_16x16x32_bf16(pf, vf, oc[dt], 0, 0, 0);
    }
  }

#pragma unroll
  for (int dt = 0; dt < 4; ++dt)
#pragma unroll
    for (int rr = 0; rr < 4; ++rr) {
      int m = s0 + q4 * 4 + rr;
      int d = dt * 16 + r16;
      out[((size_t)b * 4096 + m) * 1280 + h * 64 + d] = f2bf(oc[dt][rr]);
    }
}

// ---------- launch ----------
extern "C" void kernel_launch(void* const* d_in, const int* in_sizes, int n_in,
                              void* d_out, int out_size, void* d_ws, size_t ws_size,
                              hipStream_t stream) {
  const float* x    = (const float*)d_in[0];
  const float* ctx  = (const float*)d_in[1];
  const float* scal = (const float*)d_in[2];
  // d_in[3] = num_img_token (fixed 16; eos = 77)
  const float* Wq   = (const float*)d_in[4];
  const float* Wk   = (const float*)d_in[5];
  const float* Wv   = (const float*)d_in[6];
  const float* Wkip = (const float*)d_in[7];
  const float* Wvip = (const float*)d_in[8];
  const float* Wout = (const float*)d_in[9];
  const float* bout = (const float*)d_in[10];
  float* out = (float*)d_out;

  char* ws = (char*)d_ws;
  size_t off = 0;
  auto alloc = [&](size_t elems) -> short* {
    short* p = (short*)(ws + off);
    off += (elems * 2 + 255) & ~(size_t)255;
    return p;
  };
  short* xb    = alloc(32768UL * 1280);   // also reused as attn output (x dead after Q proj)
  short* txtb  = alloc(616UL * 2048);
  short* imgb  = alloc(128UL * 2048);
  short* Wqb   = alloc(1280UL * 1280);
  short* Wkvb  = alloc(2UL * 1280 * 2048);
  short* Wkvip = alloc(2UL * 1280 * 2048);
  short* Woutb = alloc(1280UL * 1280);
  short* qb    = alloc(32768UL * 1280);   // (b,h,4096,64)
  short* kb    = alloc(2UL * 160 * 77 * 64);
  short* kib   = alloc(2UL * 160 * 16 * 64);
  short* vb    = kb  + 160UL * 77 * 64;
  short* vib   = kib + 160UL * 16 * 64;
  short* attnb = xb;

  auto cvt = [&](const float* s, short* d, long n) {
    int blocks = (int)((n / 4 + 255) / 256);
    k_cvt<<<blocks, 256, 0, stream>>>(s, d, (int)n);
  };
  cvt(x, xb, 32768L * 1280);
  cvt(Wq, Wqb, 1280L * 1280);
  cvt(Wk,   Wkvb,                 1280L * 2048);
  cvt(Wv,   Wkvb + 1280L * 2048,  1280L * 2048);
  cvt(Wkip, Wkvip,                1280L * 2048);
  cvt(Wvip, Wkvip + 1280L * 2048, 1280L * 2048);
  cvt(Wout, Woutb, 1280L * 1280);
  {
    long n1 = 8L * 77 * 2048;
    k_cvt_ctx<<<(int)((n1 / 4 + 255) / 256), 256, 0, stream>>>(ctx, txtb, 77, 0);
    long n2 = 8L * 16 * 2048;
    k_cvt_ctx<<<(int)((n2 / 4 + 255) / 256), 256, 0, stream>>>(ctx, imgb, 16, 77);
  }

  { dim3 g(5, 128); k_gemm256<0><<<g, 512, 0, stream>>>(xb, Wqb, qb, nullptr, 32768, 1280, 1280, 4096); }
  { dim3 g(20, 5);
    k_gemm<0><<<g, 256, 0, stream>>>(txtb, Wkvb, kb, nullptr, 616, 2560, 2048, 77); }
  { dim3 g(20, 1);
    k_gemm<0><<<g, 256, 0, stream>>>(imgb, Wkvip, kib, nullptr, 128, 2560, 2048, 16); }
  { dim3 g(64, 20, 8);
    k_attn<<<g, 256, 0, stream>>>(qb, kb, vb, kib, vib, scal, attnb); }
  { dim3 g(5, 128);
    k_gemm256<1><<<g, 512, 0, stream>>>(attnb, Woutb, out, bout, 32768, 1280, 1280, 1); }
}